// Round 1
// baseline (115.701 us; speedup 1.0000x reference)
//
#include <hip/hip_runtime.h>
#include <hip/hip_bf16.h>
#include <math.h>

#define NSEQ 512
#define EMB 256
#define BATCH 2
#define HEADS 8
#define DH 32

// order-preserving float<->uint encoding for atomic min/max
__device__ __forceinline__ unsigned fenc(float f) {
    unsigned u = __float_as_uint(f);
    return (u & 0x80000000u) ? ~u : (u | 0x80000000u);
}
__device__ __forceinline__ float fdec(unsigned e) {
    unsigned u = (e & 0x80000000u) ? (e ^ 0x80000000u) : ~e;
    return __uint_as_float(u);
}

__device__ __forceinline__ float dot4acc(float acc, float4 a, float4 b) {
    acc = fmaf(a.x, b.x, acc);
    acc = fmaf(a.y, b.y, acc);
    acc = fmaf(a.z, b.z, acc);
    acc = fmaf(a.w, b.w, acc);
    return acc;
}

// K1: fused Q/K/V/P projections + per-(batch,channel) min/max of P via atomics.
// grid 256 blocks x 256 threads; block handles 4 rows of x.
__global__ __launch_bounds__(256) void k_proj(
    const float* __restrict__ x,
    const float* __restrict__ Wq, const float* __restrict__ bq,
    const float* __restrict__ Wk, const float* __restrict__ bk,
    const float* __restrict__ Wv, const float* __restrict__ bv,
    const float* __restrict__ Wr,
    float* __restrict__ Q, float* __restrict__ K,
    float* __restrict__ V, float* __restrict__ P,
    unsigned* __restrict__ maxEnc, unsigned* __restrict__ minEnc)
{
    __shared__ float xs[4][EMB];
    const int t = threadIdx.x;
    const int r0 = blockIdx.x * 4;
    {
        int row = t >> 6, c4 = t & 63;
        ((float4*)xs[row])[c4] = ((const float4*)(x + (size_t)(r0 + row) * EMB))[c4];
    }
    __syncthreads();

    const int c = t;
    const float4* wq = (const float4*)(Wq + (size_t)c * EMB);
    const float4* wk = (const float4*)(Wk + (size_t)c * EMB);
    const float4* wv = (const float4*)(Wv + (size_t)c * EMB);
    const float4* wr = (const float4*)(Wr + (size_t)c * EMB);

    float aq[4] = {0.f,0.f,0.f,0.f};
    float ak[4] = {0.f,0.f,0.f,0.f};
    float av[4] = {0.f,0.f,0.f,0.f};
    float ap[4] = {0.f,0.f,0.f,0.f};

    #pragma unroll 4
    for (int k4 = 0; k4 < 64; ++k4) {
        float4 q4 = wq[k4];
        float4 kk = wk[k4];
        float4 v4 = wv[k4];
        float4 rr = wr[k4];
        #pragma unroll
        for (int r = 0; r < 4; ++r) {
            float4 xv = ((const float4*)xs[r])[k4];
            aq[r] = dot4acc(aq[r], xv, q4);
            ak[r] = dot4acc(ak[r], xv, kk);
            av[r] = dot4acc(av[r], xv, v4);
            ap[r] = dot4acc(ap[r], xv, rr);
        }
    }

    float mx = ap[0], mn = ap[0];
    #pragma unroll
    for (int r = 0; r < 4; ++r) {
        size_t off = (size_t)(r0 + r) * EMB + c;
        Q[off] = aq[r] + bq[c];
        K[off] = ak[r] + bk[c];
        V[off] = av[r] + bv[c];
        P[off] = ap[r];
        mx = fmaxf(mx, ap[r]);
        mn = fminf(mn, ap[r]);
    }
    const int b = r0 >> 9;  // 512 rows per batch, blocks never straddle
    atomicMax(&maxEnc[b * EMB + c], fenc(mx));
    atomicMin(&minEnc[b * EMB + c], fenc(mn));
}

// K2: attention. grid (16 q-tiles, 8 heads, 2 batches) x 256 threads.
// Each block: 32 q rows, all 512 keys (4 chunks of 128 staged in LDS).
// Thread (tq,tk): q rows {2tq, 2tq+1}, private keys {tk+16j}, full 32-d PV partials.
__global__ __launch_bounds__(256) void k_attn(
    const float* __restrict__ Q, const float* __restrict__ K,
    const float* __restrict__ V, const float* __restrict__ P,
    const unsigned* __restrict__ maxEnc, const unsigned* __restrict__ minEnc,
    const float* __restrict__ br, float* __restrict__ attnw)
{
    __shared__ float ks[128][36];
    __shared__ float vs[128][36];

    const int t = threadIdx.x;
    const int q0 = blockIdx.x * 32;
    const int h = blockIdx.y;
    const int b = blockIdx.z;
    const int e0 = h * DH;
    const int tq = t >> 4, tk = t & 15;
    const float scale = 0.17677669529663687f;  // 1/sqrt(32)

    // Q_r rows into registers: Qr = Q + maxP - P + br
    float4 qreg[2][8];
    #pragma unroll
    for (int r = 0; r < 2; ++r) {
        size_t m = (size_t)(b * NSEQ + q0 + 2 * tq + r);
        const float4* Q4 = (const float4*)(Q + m * EMB + e0);
        const float4* P4 = (const float4*)(P + m * EMB + e0);
        const float4* B4 = (const float4*)(br + e0);
        const uint4* M4 = (const uint4*)(maxEnc + b * EMB + e0);
        #pragma unroll
        for (int i = 0; i < 8; ++i) {
            float4 qv = Q4[i], pv = P4[i], bv = B4[i];
            uint4 me = M4[i];
            float4 o;
            o.x = qv.x + fdec(me.x) - pv.x + bv.x;
            o.y = qv.y + fdec(me.y) - pv.y + bv.y;
            o.z = qv.z + fdec(me.z) - pv.z + bv.z;
            o.w = qv.w + fdec(me.w) - pv.w + bv.w;
            qreg[r][i] = o;
        }
    }

    float m_run[2] = {-1e30f, -1e30f};
    float l_run[2] = {0.f, 0.f};
    float4 pacc[2][8];
    #pragma unroll
    for (int r = 0; r < 2; ++r)
        #pragma unroll
        for (int i = 0; i < 8; ++i)
            pacc[r][i] = make_float4(0.f, 0.f, 0.f, 0.f);

    for (int kc = 0; kc < 4; ++kc) {
        __syncthreads();
        // stage K_r = K + P - minP + br, and V
        #pragma unroll
        for (int i = 0; i < 4; ++i) {
            int f4 = t + 256 * i;
            int row = f4 >> 3, c4 = f4 & 7;
            size_t m = (size_t)(b * NSEQ + kc * 128 + row);
            float4 kv = ((const float4*)(K + m * EMB + e0))[c4];
            float4 pv = ((const float4*)(P + m * EMB + e0))[c4];
            float4 bv = ((const float4*)(br + e0))[c4];
            uint4 mn = ((const uint4*)(minEnc + b * EMB + e0))[c4];
            float4 kr;
            kr.x = kv.x + pv.x - fdec(mn.x) + bv.x;
            kr.y = kv.y + pv.y - fdec(mn.y) + bv.y;
            kr.z = kv.z + pv.z - fdec(mn.z) + bv.z;
            kr.w = kv.w + pv.w - fdec(mn.w) + bv.w;
            ((float4*)&ks[row][0])[c4] = kr;
            ((float4*)&vs[row][0])[c4] = ((const float4*)(V + m * EMB + e0))[c4];
        }
        __syncthreads();

        // scores for this thread's 8 keys x 2 q rows
        float p[2][8];
        float mloc[2] = {-1e30f, -1e30f};
        #pragma unroll
        for (int j = 0; j < 8; ++j) {
            int kj = tk + 16 * j;
            const float4* krow = (const float4*)&ks[kj][0];
            float s0 = 0.f, s1 = 0.f;
            #pragma unroll
            for (int i = 0; i < 8; ++i) {
                float4 kf = krow[i];
                s0 = dot4acc(s0, qreg[0][i], kf);
                s1 = dot4acc(s1, qreg[1][i], kf);
            }
            p[0][j] = s0 * scale;
            p[1][j] = s1 * scale;
            mloc[0] = fmaxf(mloc[0], p[0][j]);
            mloc[1] = fmaxf(mloc[1], p[1][j]);
        }
        // row max across the 16 tk lanes (bits 0-3 of lane id)
        #pragma unroll
        for (int off = 1; off < 16; off <<= 1) {
            mloc[0] = fmaxf(mloc[0], __shfl_xor(mloc[0], off));
            mloc[1] = fmaxf(mloc[1], __shfl_xor(mloc[1], off));
        }
        // online softmax update
        #pragma unroll
        for (int r = 0; r < 2; ++r) {
            float m_new = fmaxf(m_run[r], mloc[r]);
            float sc = __expf(m_run[r] - m_new);
            m_run[r] = m_new;
            float ls = 0.f;
            #pragma unroll
            for (int j = 0; j < 8; ++j) {
                p[r][j] = __expf(p[r][j] - m_new);
                ls += p[r][j];
            }
            #pragma unroll
            for (int off = 1; off < 16; off <<= 1) ls += __shfl_xor(ls, off);
            l_run[r] = l_run[r] * sc + ls;
            #pragma unroll
            for (int i = 0; i < 8; ++i) {
                pacc[r][i].x *= sc; pacc[r][i].y *= sc;
                pacc[r][i].z *= sc; pacc[r][i].w *= sc;
            }
        }
        // PV over private keys
        #pragma unroll
        for (int j = 0; j < 8; ++j) {
            int kj = tk + 16 * j;
            const float4* vrow = (const float4*)&vs[kj][0];
            float p0 = p[0][j], p1 = p[1][j];
            #pragma unroll
            for (int i = 0; i < 8; ++i) {
                float4 vf = vrow[i];
                pacc[0][i].x = fmaf(p0, vf.x, pacc[0][i].x);
                pacc[0][i].y = fmaf(p0, vf.y, pacc[0][i].y);
                pacc[0][i].z = fmaf(p0, vf.z, pacc[0][i].z);
                pacc[0][i].w = fmaf(p0, vf.w, pacc[0][i].w);
                pacc[1][i].x = fmaf(p1, vf.x, pacc[1][i].x);
                pacc[1][i].y = fmaf(p1, vf.y, pacc[1][i].y);
                pacc[1][i].z = fmaf(p1, vf.z, pacc[1][i].z);
                pacc[1][i].w = fmaf(p1, vf.w, pacc[1][i].w);
            }
        }
    }

    // butterfly-sum PV partials across the 16 tk lanes
    #pragma unroll
    for (int r = 0; r < 2; ++r) {
        #pragma unroll
        for (int i = 0; i < 8; ++i) {
            float4 v = pacc[r][i];
            #pragma unroll
            for (int off = 1; off < 16; off <<= 1) {
                v.x += __shfl_xor(v.x, off);
                v.y += __shfl_xor(v.y, off);
                v.z += __shfl_xor(v.z, off);
                v.w += __shfl_xor(v.w, off);
            }
            pacc[r][i] = v;
        }
    }

    // write: thread owns output channels 2tk, 2tk+1
    #pragma unroll
    for (int r = 0; r < 2; ++r) {
        size_t m = (size_t)(b * NSEQ + q0 + 2 * tq + r);
        float inv = 1.f / l_run[r];
        float4 v = pacc[r][tk >> 1];
        float2 o;
        o.x = ((tk & 1) ? v.z : v.x) * inv;
        o.y = ((tk & 1) ? v.w : v.y) * inv;
        *((float2*)(attnw + m * EMB + e0 + 2 * tk)) = o;
    }
}

// K3: out-projection + residual + LN + LN. grid 256 x 256; block handles 4 rows.
__global__ __launch_bounds__(256) void k_out(
    const float* __restrict__ attnw, const float* __restrict__ x,
    const float* __restrict__ Wo, const float* __restrict__ bo,
    const float* __restrict__ g1, const float* __restrict__ b1,
    const float* __restrict__ g2, const float* __restrict__ b2,
    float* __restrict__ out)
{
    __shared__ float as_[4][EMB];
    __shared__ float red[4][4][2];  // [wave][row][{sum, sumsq}]

    const int t = threadIdx.x;
    const int r0 = blockIdx.x * 4;
    {
        int row = t >> 6, c4 = t & 63;
        ((float4*)as_[row])[c4] = ((const float4*)(attnw + (size_t)(r0 + row) * EMB))[c4];
    }
    __syncthreads();

    const int c = t;
    const float4* wo = (const float4*)(Wo + (size_t)c * EMB);
    float acc[4] = {0.f,0.f,0.f,0.f};
    #pragma unroll 4
    for (int k4 = 0; k4 < 64; ++k4) {
        float4 w = wo[k4];
        #pragma unroll
        for (int r = 0; r < 4; ++r) {
            float4 a = ((const float4*)as_[r])[k4];
            acc[r] = dot4acc(acc[r], a, w);
        }
    }

    float y[4];
    #pragma unroll
    for (int r = 0; r < 4; ++r)
        y[r] = x[(size_t)(r0 + r) * EMB + c] + acc[r] + bo[c];

    const int wid = t >> 6, lane = t & 63;

    // LN1
    #pragma unroll
    for (int r = 0; r < 4; ++r) {
        float s = y[r], s2 = y[r] * y[r];
        #pragma unroll
        for (int off = 32; off > 0; off >>= 1) {
            s  += __shfl_xor(s, off);
            s2 += __shfl_xor(s2, off);
        }
        if (lane == 0) { red[wid][r][0] = s; red[wid][r][1] = s2; }
    }
    __syncthreads();
    float t1[4];
    #pragma unroll
    for (int r = 0; r < 4; ++r) {
        float s  = red[0][r][0] + red[1][r][0] + red[2][r][0] + red[3][r][0];
        float s2 = red[0][r][1] + red[1][r][1] + red[2][r][1] + red[3][r][1];
        float mu = s * (1.f / EMB);
        float var = s2 * (1.f / EMB) - mu * mu;
        float rs = rsqrtf(var + 1e-5f);
        t1[r] = (y[r] - mu) * rs * g1[c] + b1[c];
    }
    __syncthreads();

    // LN2
    #pragma unroll
    for (int r = 0; r < 4; ++r) {
        float s = t1[r], s2 = t1[r] * t1[r];
        #pragma unroll
        for (int off = 32; off > 0; off >>= 1) {
            s  += __shfl_xor(s, off);
            s2 += __shfl_xor(s2, off);
        }
        if (lane == 0) { red[wid][r][0] = s; red[wid][r][1] = s2; }
    }
    __syncthreads();
    #pragma unroll
    for (int r = 0; r < 4; ++r) {
        float s  = red[0][r][0] + red[1][r][0] + red[2][r][0] + red[3][r][0];
        float s2 = red[0][r][1] + red[1][r][1] + red[2][r][1] + red[3][r][1];
        float mu = s * (1.f / EMB);
        float var = s2 * (1.f / EMB) - mu * mu;
        float rs = rsqrtf(var + 1e-5f);
        out[(size_t)(r0 + r) * EMB + c] = (t1[r] - mu) * rs * g2[c] + b2[c];
    }
}

extern "C" void kernel_launch(void* const* d_in, const int* in_sizes, int n_in,
                              void* d_out, int out_size, void* d_ws, size_t ws_size,
                              hipStream_t stream)
{
    const float* x  = (const float*)d_in[0];
    const float* Wq = (const float*)d_in[1];
    const float* bq = (const float*)d_in[2];
    const float* Wk = (const float*)d_in[3];
    const float* bk = (const float*)d_in[4];
    const float* Wv = (const float*)d_in[5];
    const float* bv = (const float*)d_in[6];
    const float* Wr = (const float*)d_in[7];
    const float* br = (const float*)d_in[8];
    const float* Wo = (const float*)d_in[9];
    const float* bo = (const float*)d_in[10];
    const float* g1 = (const float*)d_in[11];
    const float* b1 = (const float*)d_in[12];
    const float* g2 = (const float*)d_in[13];
    const float* b2 = (const float*)d_in[14];
    float* out = (float*)d_out;
    float* ws = (float*)d_ws;

    float* Q     = ws;                 // 1024*256
    float* Km    = ws + 262144;
    float* Vm    = ws + 524288;
    float* Pm    = ws + 786432;
    float* attnw = ws + 1048576;
    unsigned* maxEnc = (unsigned*)(ws + 1310720);  // 512
    unsigned* minEnc = maxEnc + 512;               // 512

    hipMemsetAsync(maxEnc, 0x00, 512 * sizeof(unsigned), stream);
    hipMemsetAsync(minEnc, 0xFF, 512 * sizeof(unsigned), stream);

    k_proj<<<256, 256, 0, stream>>>(x, Wq, bq, Wk, bk, Wv, bv, Wr,
                                    Q, Km, Vm, Pm, maxEnc, minEnc);
    k_attn<<<dim3(16, 8, 2), 256, 0, stream>>>(Q, Km, Vm, Pm, maxEnc, minEnc,
                                               br, attnw);
    k_out<<<256, 256, 0, stream>>>(attnw, x, Wo, bo, g1, b1, g2, b2, out);
}

// Round 2
// 94.204 us; speedup vs baseline: 1.2282x; 1.2282x over previous
//
#include <hip/hip_runtime.h>
#include <hip/hip_bf16.h>
#include <math.h>

#define NSEQ 512
#define EMB 256

// order-preserving float<->uint encoding for atomic min/max
__device__ __forceinline__ unsigned fenc(float f) {
    unsigned u = __float_as_uint(f);
    return (u & 0x80000000u) ? ~u : (u | 0x80000000u);
}
__device__ __forceinline__ float fdec(unsigned e) {
    unsigned u = (e & 0x80000000u) ? (e ^ 0x80000000u) : ~e;
    return __uint_as_float(u);
}

__device__ __forceinline__ float dot4acc(float acc, float4 a, float4 b) {
    acc = fmaf(a.x, b.x, acc);
    acc = fmaf(a.y, b.y, acc);
    acc = fmaf(a.z, b.z, acc);
    acc = fmaf(a.w, b.w, acc);
    return acc;
}

// K0: build Wall[1024][256] = rows [Wq-Wr ; Wk+Wr ; Wv ; Wr]; init min/max atomics.
__global__ __launch_bounds__(256) void k_wprep(
    const float* __restrict__ Wq, const float* __restrict__ Wk,
    const float* __restrict__ Wv, const float* __restrict__ Wr,
    float* __restrict__ Wall,
    unsigned* __restrict__ maxEnc, unsigned* __restrict__ minEnc)
{
    const int t = threadIdx.x;
    const int idx = blockIdx.x * 256 + t;   // float4 index, 65536 total
    const int n = idx >> 6, k4 = idx & 63;
    const float4* q4 = (const float4*)Wq;
    const float4* kk4 = (const float4*)Wk;
    const float4* v4 = (const float4*)Wv;
    const float4* r4 = (const float4*)Wr;
    float4 o;
    if (n < 256) {
        float4 a = q4[n * 64 + k4], b = r4[n * 64 + k4];
        o = make_float4(a.x - b.x, a.y - b.y, a.z - b.z, a.w - b.w);
    } else if (n < 512) {
        float4 a = kk4[(n - 256) * 64 + k4], b = r4[(n - 256) * 64 + k4];
        o = make_float4(a.x + b.x, a.y + b.y, a.z + b.z, a.w + b.w);
    } else if (n < 768) {
        o = v4[(n - 512) * 64 + k4];
    } else {
        o = r4[(n - 768) * 64 + k4];
    }
    ((float4*)Wall)[idx] = o;
    if (blockIdx.x == 0) {
        maxEnc[t] = 0u;            maxEnc[256 + t] = 0u;
        minEnc[t] = 0xFFFFFFFFu;   minEnc[256 + t] = 0xFFFFFFFFu;
    }
}

// K1: C[1024][768] = X[1024][256] @ Wall^T (cols 0..767 stored with bias);
// cols 768..1023 (= P) are not stored: block-reduced to per-(batch,chan) min/max.
// grid (16 m-tiles, 16 n-tiles) x 256 threads; 64x64 tile, 4x4 per thread.
__global__ __launch_bounds__(256) void k_gemm_proj(
    const float* __restrict__ X, const float* __restrict__ Wall,
    const float* __restrict__ bq, const float* __restrict__ bk,
    const float* __restrict__ bv,
    float* __restrict__ C,
    unsigned* __restrict__ maxEnc, unsigned* __restrict__ minEnc)
{
    __shared__ __align__(16) float As[64][68];   // [k][m^swz], stride 272B (16B-mult)
    __shared__ __align__(16) float Bs[64][68];   // [k][n^swz]
    const int t = threadIdx.x;
    const int tx = t & 15, ty = t >> 4;
    const int m0 = blockIdx.x * 64;
    const int n0 = blockIdx.y * 64;

    float acc[4][4] = {{0.f}};

    for (int k0 = 0; k0 < 256; k0 += 64) {
        __syncthreads();
        #pragma unroll
        for (int p = 0; p < 4; ++p) {
            int row = p * 16 + ty;
            float4 a = ((const float4*)(X    + (size_t)(m0 + row) * 256 + k0))[tx];
            float4 b = ((const float4*)(Wall + (size_t)(n0 + row) * 256 + k0))[tx];
            int sr = row ^ ((tx & 3) << 2);   // k-dependent XOR: k>>2 == tx here
            As[tx * 4 + 0][sr] = a.x; As[tx * 4 + 1][sr] = a.y;
            As[tx * 4 + 2][sr] = a.z; As[tx * 4 + 3][sr] = a.w;
            Bs[tx * 4 + 0][sr] = b.x; Bs[tx * 4 + 1][sr] = b.y;
            Bs[tx * 4 + 2][sr] = b.z; Bs[tx * 4 + 3][sr] = b.w;
        }
        __syncthreads();
        #pragma unroll 16
        for (int k = 0; k < 64; ++k) {
            int s = ((k >> 2) & 3) << 2;
            float4 a4 = *(const float4*)&As[k][(ty * 4) ^ s];
            float4 b4 = *(const float4*)&Bs[k][(tx * 4) ^ s];
            acc[0][0] = fmaf(a4.x, b4.x, acc[0][0]);
            acc[0][1] = fmaf(a4.x, b4.y, acc[0][1]);
            acc[0][2] = fmaf(a4.x, b4.z, acc[0][2]);
            acc[0][3] = fmaf(a4.x, b4.w, acc[0][3]);
            acc[1][0] = fmaf(a4.y, b4.x, acc[1][0]);
            acc[1][1] = fmaf(a4.y, b4.y, acc[1][1]);
            acc[1][2] = fmaf(a4.y, b4.z, acc[1][2]);
            acc[1][3] = fmaf(a4.y, b4.w, acc[1][3]);
            acc[2][0] = fmaf(a4.z, b4.x, acc[2][0]);
            acc[2][1] = fmaf(a4.z, b4.y, acc[2][1]);
            acc[2][2] = fmaf(a4.z, b4.z, acc[2][2]);
            acc[2][3] = fmaf(a4.z, b4.w, acc[2][3]);
            acc[3][0] = fmaf(a4.w, b4.x, acc[3][0]);
            acc[3][1] = fmaf(a4.w, b4.y, acc[3][1]);
            acc[3][2] = fmaf(a4.w, b4.z, acc[3][2]);
            acc[3][3] = fmaf(a4.w, b4.w, acc[3][3]);
        }
    }

    const int seg = n0 >> 8;  // 0:Q'(+bq) 1:K'(+bk) 2:V(+bv) 3:P(min/max only)
    if (seg < 3) {
        const float* bias = (seg == 0) ? bq : ((seg == 1) ? bk : bv);
        float4 bf = ((const float4*)(bias + (n0 & 255)))[tx];
        #pragma unroll
        for (int r = 0; r < 4; ++r) {
            float4 o = make_float4(acc[r][0] + bf.x, acc[r][1] + bf.y,
                                   acc[r][2] + bf.z, acc[r][3] + bf.w);
            *((float4*)(C + (size_t)(m0 + ty * 4 + r) * 768 + n0 + tx * 4)) = o;
        }
    } else {
        __syncthreads();
        float* redmin = &As[0][0];
        float* redmax = &Bs[0][0];
        #pragma unroll
        for (int c = 0; c < 4; ++c) {
            float mn = fminf(fminf(acc[0][c], acc[1][c]), fminf(acc[2][c], acc[3][c]));
            float mx = fmaxf(fmaxf(acc[0][c], acc[1][c]), fmaxf(acc[2][c], acc[3][c]));
            redmin[ty * 64 + tx * 4 + c] = mn;
            redmax[ty * 64 + tx * 4 + c] = mx;
        }
        __syncthreads();
        if (t < 64) {
            float mn = redmin[t], mx = redmax[t];
            #pragma unroll
            for (int g = 1; g < 16; ++g) {
                mn = fminf(mn, redmin[g * 64 + t]);
                mx = fmaxf(mx, redmax[g * 64 + t]);
            }
            const int b = m0 >> 9;
            const int c = (n0 - 768) + t;
            atomicMin(&minEnc[b * 256 + c], fenc(mn));
            atomicMax(&maxEnc[b * 256 + c], fenc(mx));
        }
    }
}

// K2: attention. grid (32 q-tiles of 16 rows, 8 heads, 2 batches) x 256 threads.
// tq=t>>5 owns rows {2tq,2tq+1}; tk=t&31 owns 4 keys per 128-key chunk.
__global__ __launch_bounds__(256) void k_attn(
    const float* __restrict__ C,
    const unsigned* __restrict__ maxEnc, const unsigned* __restrict__ minEnc,
    const float* __restrict__ br, float* __restrict__ attnw)
{
    __shared__ __align__(16) float ks[128][36];
    __shared__ __align__(16) float vs[128][36];
    __shared__ __align__(16) float qadd[32];
    __shared__ __align__(16) float kadd[32];

    const int t = threadIdx.x;
    const int q0 = blockIdx.x * 16;
    const int h  = blockIdx.y;
    const int b  = blockIdx.z;
    const int e0 = h * 32;
    const int tq = t >> 5, tk = t & 31;
    const float scale = 0.17677669529663687f;  // 1/sqrt(32)

    if (t < 32) {
        qadd[t] = fdec(maxEnc[b * 256 + e0 + t]) + br[e0 + t];
        kadd[t] = br[e0 + t] - fdec(minEnc[b * 256 + e0 + t]);
    }
    __syncthreads();

    // Qr = C_q + (maxP + br)
    float4 qreg[2][8];
    #pragma unroll
    for (int r = 0; r < 2; ++r) {
        size_t m = (size_t)(b * NSEQ + q0 + 2 * tq + r);
        const float4* Crow = (const float4*)(C + m * 768 + e0);
        #pragma unroll
        for (int i = 0; i < 8; ++i) {
            float4 qv = Crow[i];
            float4 ad = ((const float4*)qadd)[i];
            qreg[r][i] = make_float4(qv.x + ad.x, qv.y + ad.y, qv.z + ad.z, qv.w + ad.w);
        }
    }

    float m_run[2] = {-1e30f, -1e30f};
    float l_run[2] = {0.f, 0.f};
    float4 pacc[2][8];
    #pragma unroll
    for (int r = 0; r < 2; ++r)
        #pragma unroll
        for (int i = 0; i < 8; ++i)
            pacc[r][i] = make_float4(0.f, 0.f, 0.f, 0.f);

    for (int kc = 0; kc < 4; ++kc) {
        __syncthreads();
        #pragma unroll
        for (int i = 0; i < 4; ++i) {
            int f4 = t + 256 * i;
            int row = f4 >> 3, c4 = f4 & 7;
            size_t m = (size_t)(b * NSEQ + kc * 128 + row);
            float4 kv = ((const float4*)(C + m * 768 + 256 + e0))[c4];
            float4 ad = ((const float4*)kadd)[c4];
            ((float4*)&ks[row][0])[c4] =
                make_float4(kv.x + ad.x, kv.y + ad.y, kv.z + ad.z, kv.w + ad.w);
            ((float4*)&vs[row][0])[c4] = ((const float4*)(C + m * 768 + 512 + e0))[c4];
        }
        __syncthreads();

        float p[2][4];
        float mloc[2] = {-1e30f, -1e30f};
        #pragma unroll
        for (int j = 0; j < 4; ++j) {
            int kj = tk + 32 * j;
            const float4* krow = (const float4*)&ks[kj][0];
            float s0 = 0.f, s1 = 0.f;
            #pragma unroll
            for (int i = 0; i < 8; ++i) {
                float4 kf = krow[i];
                s0 = dot4acc(s0, qreg[0][i], kf);
                s1 = dot4acc(s1, qreg[1][i], kf);
            }
            p[0][j] = s0 * scale;
            p[1][j] = s1 * scale;
            mloc[0] = fmaxf(mloc[0], p[0][j]);
            mloc[1] = fmaxf(mloc[1], p[1][j]);
        }
        #pragma unroll
        for (int off = 1; off < 32; off <<= 1) {
            mloc[0] = fmaxf(mloc[0], __shfl_xor(mloc[0], off));
            mloc[1] = fmaxf(mloc[1], __shfl_xor(mloc[1], off));
        }
        #pragma unroll
        for (int r = 0; r < 2; ++r) {
            float m_new = fmaxf(m_run[r], mloc[r]);
            float sc = __expf(m_run[r] - m_new);
            m_run[r] = m_new;
            float ls = 0.f;
            #pragma unroll
            for (int j = 0; j < 4; ++j) {
                p[r][j] = __expf(p[r][j] - m_new);
                ls += p[r][j];
            }
            #pragma unroll
            for (int off = 1; off < 32; off <<= 1) ls += __shfl_xor(ls, off);
            l_run[r] = l_run[r] * sc + ls;
            #pragma unroll
            for (int i = 0; i < 8; ++i) {
                pacc[r][i].x *= sc; pacc[r][i].y *= sc;
                pacc[r][i].z *= sc; pacc[r][i].w *= sc;
            }
        }
        #pragma unroll
        for (int j = 0; j < 4; ++j) {
            int kj = tk + 32 * j;
            const float4* vrow = (const float4*)&vs[kj][0];
            float p0 = p[0][j], p1 = p[1][j];
            #pragma unroll
            for (int i = 0; i < 8; ++i) {
                float4 vf = vrow[i];
                pacc[0][i].x = fmaf(p0, vf.x, pacc[0][i].x);
                pacc[0][i].y = fmaf(p0, vf.y, pacc[0][i].y);
                pacc[0][i].z = fmaf(p0, vf.z, pacc[0][i].z);
                pacc[0][i].w = fmaf(p0, vf.w, pacc[0][i].w);
                pacc[1][i].x = fmaf(p1, vf.x, pacc[1][i].x);
                pacc[1][i].y = fmaf(p1, vf.y, pacc[1][i].y);
                pacc[1][i].z = fmaf(p1, vf.z, pacc[1][i].z);
                pacc[1][i].w = fmaf(p1, vf.w, pacc[1][i].w);
            }
        }
    }

    // butterfly-sum across the 32 tk lanes
    #pragma unroll
    for (int r = 0; r < 2; ++r) {
        #pragma unroll
        for (int i = 0; i < 8; ++i) {
            float4 v = pacc[r][i];
            #pragma unroll
            for (int off = 1; off < 32; off <<= 1) {
                v.x += __shfl_xor(v.x, off);
                v.y += __shfl_xor(v.y, off);
                v.z += __shfl_xor(v.z, off);
                v.w += __shfl_xor(v.w, off);
            }
            pacc[r][i] = v;
        }
    }

    // lane tk writes channel tk (static-index select, no scratch)
    #pragma unroll
    for (int r = 0; r < 2; ++r) {
        float val = 0.f;
        #pragma unroll
        for (int i = 0; i < 8; ++i) {
            float4 v = pacc[r][i];
            int cc = tk & 3;
            float comp = (cc == 0) ? v.x : ((cc == 1) ? v.y : ((cc == 2) ? v.z : v.w));
            if ((tk >> 2) == i) val = comp;
        }
        size_t m = (size_t)(b * NSEQ + q0 + 2 * tq + r);
        attnw[m * 256 + e0 + tk] = val / l_run[r];
    }
}

// K3: out-projection + residual + LN + LN. grid 256 x 256; block handles 4 rows.
// Wo staged into LDS in 8 chunks of 32 k-cols (coalesced bulk loads).
__global__ __launch_bounds__(256) void k_out(
    const float* __restrict__ attnw, const float* __restrict__ x,
    const float* __restrict__ Wo, const float* __restrict__ bo,
    const float* __restrict__ g1, const float* __restrict__ b1,
    const float* __restrict__ g2, const float* __restrict__ b2,
    float* __restrict__ out)
{
    __shared__ __align__(16) float as_[4][256];   // 4 rows of attnw
    __shared__ float Ws[256][33];                 // Wo[n][k-chunk], odd stride
    __shared__ float red[4][4][2];

    const int t = threadIdx.x;
    const int r0 = blockIdx.x * 4;
    {
        int row = t >> 6, c4 = t & 63;
        ((float4*)as_[row])[c4] = ((const float4*)(attnw + (size_t)(r0 + row) * 256))[c4];
    }

    float acc[4] = {0.f, 0.f, 0.f, 0.f};
    for (int kc = 0; kc < 8; ++kc) {
        __syncthreads();
        // stage Wo[:, kc*32 .. kc*32+31]
        #pragma unroll
        for (int p = 0; p < 8; ++p) {
            int n = p * 32 + (t >> 3);
            int k4 = t & 7;
            float4 w = ((const float4*)(Wo + (size_t)n * 256 + kc * 32))[k4];
            Ws[n][k4 * 4 + 0] = w.x; Ws[n][k4 * 4 + 1] = w.y;
            Ws[n][k4 * 4 + 2] = w.z; Ws[n][k4 * 4 + 3] = w.w;
        }
        __syncthreads();
        #pragma unroll
        for (int kk4 = 0; kk4 < 8; ++kk4) {
            int kbase = kc * 32 + kk4 * 4;
            float4 a0 = *(const float4*)&as_[0][kbase];
            float4 a1 = *(const float4*)&as_[1][kbase];
            float4 a2 = *(const float4*)&as_[2][kbase];
            float4 a3 = *(const float4*)&as_[3][kbase];
            float w0 = Ws[t][kk4 * 4 + 0];
            float w1 = Ws[t][kk4 * 4 + 1];
            float w2 = Ws[t][kk4 * 4 + 2];
            float w3 = Ws[t][kk4 * 4 + 3];
            acc[0] = fmaf(a0.x, w0, acc[0]); acc[0] = fmaf(a0.y, w1, acc[0]);
            acc[0] = fmaf(a0.z, w2, acc[0]); acc[0] = fmaf(a0.w, w3, acc[0]);
            acc[1] = fmaf(a1.x, w0, acc[1]); acc[1] = fmaf(a1.y, w1, acc[1]);
            acc[1] = fmaf(a1.z, w2, acc[1]); acc[1] = fmaf(a1.w, w3, acc[1]);
            acc[2] = fmaf(a2.x, w0, acc[2]); acc[2] = fmaf(a2.y, w1, acc[2]);
            acc[2] = fmaf(a2.z, w2, acc[2]); acc[2] = fmaf(a2.w, w3, acc[2]);
            acc[3] = fmaf(a3.x, w0, acc[3]); acc[3] = fmaf(a3.y, w1, acc[3]);
            acc[3] = fmaf(a3.z, w2, acc[3]); acc[3] = fmaf(a3.w, w3, acc[3]);
        }
    }

    const int c = t;
    float y[4];
    #pragma unroll
    for (int r = 0; r < 4; ++r)
        y[r] = x[(size_t)(r0 + r) * 256 + c] + acc[r] + bo[c];

    const int wid = t >> 6, lane = t & 63;

    // LN1
    #pragma unroll
    for (int r = 0; r < 4; ++r) {
        float s = y[r], s2 = y[r] * y[r];
        #pragma unroll
        for (int off = 32; off > 0; off >>= 1) {
            s  += __shfl_xor(s, off);
            s2 += __shfl_xor(s2, off);
        }
        if (lane == 0) { red[wid][r][0] = s; red[wid][r][1] = s2; }
    }
    __syncthreads();
    float t1[4];
    #pragma unroll
    for (int r = 0; r < 4; ++r) {
        float s  = red[0][r][0] + red[1][r][0] + red[2][r][0] + red[3][r][0];
        float s2 = red[0][r][1] + red[1][r][1] + red[2][r][1] + red[3][r][1];
        float mu = s * (1.f / 256.f);
        float var = s2 * (1.f / 256.f) - mu * mu;
        float rs = rsqrtf(var + 1e-5f);
        t1[r] = (y[r] - mu) * rs * g1[c] + b1[c];
    }
    __syncthreads();

    // LN2
    #pragma unroll
    for (int r = 0; r < 4; ++r) {
        float s = t1[r], s2 = t1[r] * t1[r];
        #pragma unroll
        for (int off = 32; off > 0; off >>= 1) {
            s  += __shfl_xor(s, off);
            s2 += __shfl_xor(s2, off);
        }
        if (lane == 0) { red[wid][r][0] = s; red[wid][r][1] = s2; }
    }
    __syncthreads();
    #pragma unroll
    for (int r = 0; r < 4; ++r) {
        float s  = red[0][r][0] + red[1][r][0] + red[2][r][0] + red[3][r][0];
        float s2 = red[0][r][1] + red[1][r][1] + red[2][r][1] + red[3][r][1];
        float mu = s * (1.f / 256.f);
        float var = s2 * (1.f / 256.f) - mu * mu;
        float rs = rsqrtf(var + 1e-5f);
        out[(size_t)(r0 + r) * 256 + c] = (t1[r] - mu) * rs * g2[c] + b2[c];
    }
}

extern "C" void kernel_launch(void* const* d_in, const int* in_sizes, int n_in,
                              void* d_out, int out_size, void* d_ws, size_t ws_size,
                              hipStream_t stream)
{
    const float* x  = (const float*)d_in[0];
    const float* Wq = (const float*)d_in[1];
    const float* bq = (const float*)d_in[2];
    const float* Wk = (const float*)d_in[3];
    const float* bk = (const float*)d_in[4];
    const float* Wv = (const float*)d_in[5];
    const float* bv = (const float*)d_in[6];
    const float* Wr = (const float*)d_in[7];
    const float* br = (const float*)d_in[8];
    const float* Wo = (const float*)d_in[9];
    const float* bo = (const float*)d_in[10];
    const float* g1 = (const float*)d_in[11];
    const float* b1 = (const float*)d_in[12];
    const float* g2 = (const float*)d_in[13];
    const float* b2 = (const float*)d_in[14];
    float* out = (float*)d_out;
    float* ws = (float*)d_ws;

    float* Wall  = ws;                     // 262144 floats
    float* C     = ws + 262144;            // 786432 floats (stride 768: Q'|K'|V)
    float* attnw = ws + 1048576;           // 262144 floats
    unsigned* maxEnc = (unsigned*)(ws + 1310720);  // 512
    unsigned* minEnc = maxEnc + 512;               // 512

    k_wprep<<<256, 256, 0, stream>>>(Wq, Wk, Wv, Wr, Wall, maxEnc, minEnc);
    k_gemm_proj<<<dim3(16, 16), 256, 0, stream>>>(x, Wall, bq, bk, bv,
                                                  C, maxEnc, minEnc);
    k_attn<<<dim3(32, 8, 2), 256, 0, stream>>>(C, maxEnc, minEnc, br, attnw);
    k_out<<<256, 256, 0, stream>>>(attnw, x, Wo, bo, g1, b1, g2, b2, out);
}

// Round 3
// 86.562 us; speedup vs baseline: 1.3366x; 1.0883x over previous
//
#include <hip/hip_runtime.h>
#include <hip/hip_bf16.h>
#include <math.h>

#define NSEQ 512
#define EMB 256

// order-preserving float<->uint encoding for atomic min/max
__device__ __forceinline__ unsigned fenc(float f) {
    unsigned u = __float_as_uint(f);
    return (u & 0x80000000u) ? ~u : (u | 0x80000000u);
}
__device__ __forceinline__ float fdec(unsigned e) {
    unsigned u = (e & 0x80000000u) ? (e ^ 0x80000000u) : ~e;
    return __uint_as_float(u);
}

__device__ __forceinline__ float dot4acc(float acc, float4 a, float4 b) {
    acc = fmaf(a.x, b.x, acc);
    acc = fmaf(a.y, b.y, acc);
    acc = fmaf(a.z, b.z, acc);
    acc = fmaf(a.w, b.w, acc);
    return acc;
}

// K1: C[1024][768] = X @ [Wq-Wr; Wk+Wr; Wv]^T (+bias), and P = X@Wr^T reduced
// to per-(batch,chan) min/max (never stored). Wall computed on the fly.
// grid (16 m-tiles, 16 n-tiles) x 256; 64x64 tile, 4x4/thread, reg-dbuf over K.
__global__ __launch_bounds__(256, 2) void k_gemm_proj(
    const float* __restrict__ X,
    const float* __restrict__ Wq, const float* __restrict__ Wk,
    const float* __restrict__ Wv, const float* __restrict__ Wr,
    const float* __restrict__ bq, const float* __restrict__ bk,
    const float* __restrict__ bv,
    float* __restrict__ C,
    unsigned* __restrict__ maxEnc, unsigned* __restrict__ minEnc)
{
    __shared__ __align__(16) float As[64][68];
    __shared__ __align__(16) float Bs[64][68];
    const int t = threadIdx.x;
    const int tx = t & 15, ty = t >> 4;
    const int m0 = blockIdx.x * 64;
    const int n0 = blockIdx.y * 64;
    const int seg = blockIdx.y >> 2;          // 0:Q' 1:K' 2:V 3:P
    const int wbase = (blockIdx.y & 3) * 64;  // row offset within the 256-row W

    float4 aR[4], bR[4];

    auto loadfrags = [&](int k0) {
        #pragma unroll
        for (int p = 0; p < 4; ++p) {
            int row = p * 16 + ty;
            aR[p] = ((const float4*)(X + (size_t)(m0 + row) * 256 + k0))[tx];
            size_t woff = (size_t)(wbase + row) * 256 + k0;
            if (seg == 0) {
                float4 a = ((const float4*)(Wq + woff))[tx];
                float4 r = ((const float4*)(Wr + woff))[tx];
                bR[p] = make_float4(a.x - r.x, a.y - r.y, a.z - r.z, a.w - r.w);
            } else if (seg == 1) {
                float4 a = ((const float4*)(Wk + woff))[tx];
                float4 r = ((const float4*)(Wr + woff))[tx];
                bR[p] = make_float4(a.x + r.x, a.y + r.y, a.z + r.z, a.w + r.w);
            } else if (seg == 2) {
                bR[p] = ((const float4*)(Wv + woff))[tx];
            } else {
                bR[p] = ((const float4*)(Wr + woff))[tx];
            }
        }
    };

    float acc[4][4] = {{0.f}};
    loadfrags(0);

    #pragma unroll
    for (int kc = 0; kc < 4; ++kc) {
        __syncthreads();
        #pragma unroll
        for (int p = 0; p < 4; ++p) {
            int row = p * 16 + ty;
            int sr = row ^ ((tx & 3) << 2);
            As[tx * 4 + 0][sr] = aR[p].x; As[tx * 4 + 1][sr] = aR[p].y;
            As[tx * 4 + 2][sr] = aR[p].z; As[tx * 4 + 3][sr] = aR[p].w;
            Bs[tx * 4 + 0][sr] = bR[p].x; Bs[tx * 4 + 1][sr] = bR[p].y;
            Bs[tx * 4 + 2][sr] = bR[p].z; Bs[tx * 4 + 3][sr] = bR[p].w;
        }
        __syncthreads();
        if (kc < 3) loadfrags((kc + 1) * 64);   // overlap with compute below
        #pragma unroll 16
        for (int k = 0; k < 64; ++k) {
            int s = ((k >> 2) & 3) << 2;
            float4 a4 = *(const float4*)&As[k][(ty * 4) ^ s];
            float4 b4 = *(const float4*)&Bs[k][(tx * 4) ^ s];
            acc[0][0] = fmaf(a4.x, b4.x, acc[0][0]);
            acc[0][1] = fmaf(a4.x, b4.y, acc[0][1]);
            acc[0][2] = fmaf(a4.x, b4.z, acc[0][2]);
            acc[0][3] = fmaf(a4.x, b4.w, acc[0][3]);
            acc[1][0] = fmaf(a4.y, b4.x, acc[1][0]);
            acc[1][1] = fmaf(a4.y, b4.y, acc[1][1]);
            acc[1][2] = fmaf(a4.y, b4.z, acc[1][2]);
            acc[1][3] = fmaf(a4.y, b4.w, acc[1][3]);
            acc[2][0] = fmaf(a4.z, b4.x, acc[2][0]);
            acc[2][1] = fmaf(a4.z, b4.y, acc[2][1]);
            acc[2][2] = fmaf(a4.z, b4.z, acc[2][2]);
            acc[2][3] = fmaf(a4.z, b4.w, acc[2][3]);
            acc[3][0] = fmaf(a4.w, b4.x, acc[3][0]);
            acc[3][1] = fmaf(a4.w, b4.y, acc[3][1]);
            acc[3][2] = fmaf(a4.w, b4.z, acc[3][2]);
            acc[3][3] = fmaf(a4.w, b4.w, acc[3][3]);
        }
    }

    if (seg < 3) {
        const float* bias = (seg == 0) ? bq : ((seg == 1) ? bk : bv);
        float4 bf = ((const float4*)(bias + (n0 & 255)))[tx];
        #pragma unroll
        for (int r = 0; r < 4; ++r) {
            float4 o = make_float4(acc[r][0] + bf.x, acc[r][1] + bf.y,
                                   acc[r][2] + bf.z, acc[r][3] + bf.w);
            *((float4*)(C + (size_t)(m0 + ty * 4 + r) * 768 + n0 + tx * 4)) = o;
        }
    } else {
        __syncthreads();
        float* redmin = &As[0][0];
        float* redmax = &Bs[0][0];
        #pragma unroll
        for (int c = 0; c < 4; ++c) {
            float mn = fminf(fminf(acc[0][c], acc[1][c]), fminf(acc[2][c], acc[3][c]));
            float mx = fmaxf(fmaxf(acc[0][c], acc[1][c]), fmaxf(acc[2][c], acc[3][c]));
            redmin[ty * 64 + tx * 4 + c] = mn;
            redmax[ty * 64 + tx * 4 + c] = mx;
        }
        __syncthreads();
        if (t < 64) {
            float mn = redmin[t], mx = redmax[t];
            #pragma unroll
            for (int g = 1; g < 16; ++g) {
                mn = fminf(mn, redmin[g * 64 + t]);
                mx = fmaxf(mx, redmax[g * 64 + t]);
            }
            const int b = m0 >> 9;
            const int c = (n0 & 255) + t;
            atomicMin(&minEnc[b * 256 + c], fenc(mn));
            atomicMax(&maxEnc[b * 256 + c], fenc(mx));
        }
    }
}

// K2: attention. grid (32 q-tiles, 8 heads, 2 batches) x 256. Reg-dbuf K/V staging.
__global__ __launch_bounds__(256, 2) void k_attn(
    const float* __restrict__ C,
    const unsigned* __restrict__ maxEnc, const unsigned* __restrict__ minEnc,
    const float* __restrict__ br, float* __restrict__ attnw)
{
    __shared__ __align__(16) float ks[128][36];
    __shared__ __align__(16) float vs[128][36];
    __shared__ __align__(16) float qadd[32];
    __shared__ __align__(16) float kadd[32];

    const int t = threadIdx.x;
    const int q0 = blockIdx.x * 16;
    const int h  = blockIdx.y;
    const int b  = blockIdx.z;
    const int e0 = h * 32;
    const int tq = t >> 5, tk = t & 31;
    const float scale = 0.17677669529663687f;  // 1/sqrt(32)

    if (t < 32) {
        qadd[t] = fdec(maxEnc[b * 256 + e0 + t]) + br[e0 + t];
        kadd[t] = br[e0 + t] - fdec(minEnc[b * 256 + e0 + t]);
    }

    float4 kR[4], vR[4];
    auto loadKV = [&](int kc) {
        #pragma unroll
        for (int i = 0; i < 4; ++i) {
            int f4 = t + 256 * i;
            int row = f4 >> 3, c4 = f4 & 7;
            size_t m = (size_t)(b * NSEQ + kc * 128 + row);
            kR[i] = ((const float4*)(C + m * 768 + 256 + e0))[c4];
            vR[i] = ((const float4*)(C + m * 768 + 512 + e0))[c4];
        }
    };
    loadKV(0);
    __syncthreads();   // qadd/kadd ready

    // Qr = C_q + (maxP + br)
    float4 qreg[2][8];
    #pragma unroll
    for (int r = 0; r < 2; ++r) {
        size_t m = (size_t)(b * NSEQ + q0 + 2 * tq + r);
        const float4* Crow = (const float4*)(C + m * 768 + e0);
        #pragma unroll
        for (int i = 0; i < 8; ++i) {
            float4 qv = Crow[i];
            float4 ad = ((const float4*)qadd)[i];
            qreg[r][i] = make_float4(qv.x + ad.x, qv.y + ad.y, qv.z + ad.z, qv.w + ad.w);
        }
    }

    float m_run[2] = {-1e30f, -1e30f};
    float l_run[2] = {0.f, 0.f};
    float4 pacc[2][8];
    #pragma unroll
    for (int r = 0; r < 2; ++r)
        #pragma unroll
        for (int i = 0; i < 8; ++i)
            pacc[r][i] = make_float4(0.f, 0.f, 0.f, 0.f);

    #pragma unroll
    for (int kc = 0; kc < 4; ++kc) {
        __syncthreads();
        #pragma unroll
        for (int i = 0; i < 4; ++i) {
            int f4 = t + 256 * i;
            int row = f4 >> 3, c4 = f4 & 7;
            float4 ad = ((const float4*)kadd)[c4];
            ((float4*)&ks[row][0])[c4] =
                make_float4(kR[i].x + ad.x, kR[i].y + ad.y, kR[i].z + ad.z, kR[i].w + ad.w);
            ((float4*)&vs[row][0])[c4] = vR[i];
        }
        __syncthreads();
        if (kc < 3) loadKV(kc + 1);   // overlap with compute below

        float p[2][4];
        float mloc[2] = {-1e30f, -1e30f};
        #pragma unroll
        for (int j = 0; j < 4; ++j) {
            int kj = tk + 32 * j;
            const float4* krow = (const float4*)&ks[kj][0];
            float s0 = 0.f, s1 = 0.f;
            #pragma unroll
            for (int i = 0; i < 8; ++i) {
                float4 kf = krow[i];
                s0 = dot4acc(s0, qreg[0][i], kf);
                s1 = dot4acc(s1, qreg[1][i], kf);
            }
            p[0][j] = s0 * scale;
            p[1][j] = s1 * scale;
            mloc[0] = fmaxf(mloc[0], p[0][j]);
            mloc[1] = fmaxf(mloc[1], p[1][j]);
        }
        #pragma unroll
        for (int off = 1; off < 32; off <<= 1) {
            mloc[0] = fmaxf(mloc[0], __shfl_xor(mloc[0], off));
            mloc[1] = fmaxf(mloc[1], __shfl_xor(mloc[1], off));
        }
        #pragma unroll
        for (int r = 0; r < 2; ++r) {
            float m_new = fmaxf(m_run[r], mloc[r]);
            float sc = __expf(m_run[r] - m_new);
            m_run[r] = m_new;
            float ls = 0.f;
            #pragma unroll
            for (int j = 0; j < 4; ++j) {
                p[r][j] = __expf(p[r][j] - m_new);
                ls += p[r][j];
            }
            #pragma unroll
            for (int off = 1; off < 32; off <<= 1) ls += __shfl_xor(ls, off);
            l_run[r] = l_run[r] * sc + ls;
            #pragma unroll
            for (int i = 0; i < 8; ++i) {
                pacc[r][i].x *= sc; pacc[r][i].y *= sc;
                pacc[r][i].z *= sc; pacc[r][i].w *= sc;
            }
        }
        #pragma unroll
        for (int j = 0; j < 4; ++j) {
            int kj = tk + 32 * j;
            const float4* vrow = (const float4*)&vs[kj][0];
            float p0 = p[0][j], p1 = p[1][j];
            #pragma unroll
            for (int i = 0; i < 8; ++i) {
                float4 vf = vrow[i];
                pacc[0][i].x = fmaf(p0, vf.x, pacc[0][i].x);
                pacc[0][i].y = fmaf(p0, vf.y, pacc[0][i].y);
                pacc[0][i].z = fmaf(p0, vf.z, pacc[0][i].z);
                pacc[0][i].w = fmaf(p0, vf.w, pacc[0][i].w);
                pacc[1][i].x = fmaf(p1, vf.x, pacc[1][i].x);
                pacc[1][i].y = fmaf(p1, vf.y, pacc[1][i].y);
                pacc[1][i].z = fmaf(p1, vf.z, pacc[1][i].z);
                pacc[1][i].w = fmaf(p1, vf.w, pacc[1][i].w);
            }
        }
    }

    // butterfly-sum across the 32 tk lanes
    #pragma unroll
    for (int r = 0; r < 2; ++r) {
        #pragma unroll
        for (int i = 0; i < 8; ++i) {
            float4 v = pacc[r][i];
            #pragma unroll
            for (int off = 1; off < 32; off <<= 1) {
                v.x += __shfl_xor(v.x, off);
                v.y += __shfl_xor(v.y, off);
                v.z += __shfl_xor(v.z, off);
                v.w += __shfl_xor(v.w, off);
            }
            pacc[r][i] = v;
        }
    }

    // lane tk writes channel tk (static-index select, no scratch)
    #pragma unroll
    for (int r = 0; r < 2; ++r) {
        float val = 0.f;
        #pragma unroll
        for (int i = 0; i < 8; ++i) {
            float4 v = pacc[r][i];
            int cc = tk & 3;
            float comp = (cc == 0) ? v.x : ((cc == 1) ? v.y : ((cc == 2) ? v.z : v.w));
            if ((tk >> 2) == i) val = comp;
        }
        size_t m = (size_t)(b * NSEQ + q0 + 2 * tq + r);
        attnw[m * 256 + e0 + tk] = val / l_run[r];
    }
}

// K3: split-K out-projection partials. grid (16 m, 4 n, 4 ksplit) x 256.
// Each block: one 64x64 tile x one 64-wide K chunk -> yPart[bz].
__global__ __launch_bounds__(256, 2) void k_ogemm(
    const float* __restrict__ A, const float* __restrict__ Wo,
    float* __restrict__ yPart)
{
    __shared__ __align__(16) float As[64][68];
    __shared__ __align__(16) float Bs[64][68];
    const int t = threadIdx.x;
    const int tx = t & 15, ty = t >> 4;
    const int m0 = blockIdx.x * 64;
    const int n0 = blockIdx.y * 64;
    const int k0 = blockIdx.z * 64;

    #pragma unroll
    for (int p = 0; p < 4; ++p) {
        int row = p * 16 + ty;
        float4 a = ((const float4*)(A  + (size_t)(m0 + row) * 256 + k0))[tx];
        float4 b = ((const float4*)(Wo + (size_t)(n0 + row) * 256 + k0))[tx];
        int sr = row ^ ((tx & 3) << 2);
        As[tx * 4 + 0][sr] = a.x; As[tx * 4 + 1][sr] = a.y;
        As[tx * 4 + 2][sr] = a.z; As[tx * 4 + 3][sr] = a.w;
        Bs[tx * 4 + 0][sr] = b.x; Bs[tx * 4 + 1][sr] = b.y;
        Bs[tx * 4 + 2][sr] = b.z; Bs[tx * 4 + 3][sr] = b.w;
    }
    __syncthreads();

    float acc[4][4] = {{0.f}};
    #pragma unroll 16
    for (int k = 0; k < 64; ++k) {
        int s = ((k >> 2) & 3) << 2;
        float4 a4 = *(const float4*)&As[k][(ty * 4) ^ s];
        float4 b4 = *(const float4*)&Bs[k][(tx * 4) ^ s];
        acc[0][0] = fmaf(a4.x, b4.x, acc[0][0]);
        acc[0][1] = fmaf(a4.x, b4.y, acc[0][1]);
        acc[0][2] = fmaf(a4.x, b4.z, acc[0][2]);
        acc[0][3] = fmaf(a4.x, b4.w, acc[0][3]);
        acc[1][0] = fmaf(a4.y, b4.x, acc[1][0]);
        acc[1][1] = fmaf(a4.y, b4.y, acc[1][1]);
        acc[1][2] = fmaf(a4.y, b4.z, acc[1][2]);
        acc[1][3] = fmaf(a4.y, b4.w, acc[1][3]);
        acc[2][0] = fmaf(a4.z, b4.x, acc[2][0]);
        acc[2][1] = fmaf(a4.z, b4.y, acc[2][1]);
        acc[2][2] = fmaf(a4.z, b4.z, acc[2][2]);
        acc[2][3] = fmaf(a4.z, b4.w, acc[2][3]);
        acc[3][0] = fmaf(a4.w, b4.x, acc[3][0]);
        acc[3][1] = fmaf(a4.w, b4.y, acc[3][1]);
        acc[3][2] = fmaf(a4.w, b4.z, acc[3][2]);
        acc[3][3] = fmaf(a4.w, b4.w, acc[3][3]);
    }

    float* dst = yPart + (size_t)blockIdx.z * (1024 * 256);
    #pragma unroll
    for (int r = 0; r < 4; ++r) {
        float4 o = make_float4(acc[r][0], acc[r][1], acc[r][2], acc[r][3]);
        *((float4*)(dst + (size_t)(m0 + ty * 4 + r) * 256 + n0 + tx * 4)) = o;
    }
}

// K4: y = x + bo + sum(yPart) ; LN1 ; LN2. grid 256 x 256; 4 rows/block.
__global__ __launch_bounds__(256) void k_lnorm(
    const float* __restrict__ yP, const float* __restrict__ x,
    const float* __restrict__ bo,
    const float* __restrict__ g1, const float* __restrict__ b1,
    const float* __restrict__ g2, const float* __restrict__ b2,
    float* __restrict__ out)
{
    __shared__ float red[4][4][2];
    const int t = threadIdx.x;
    const int r0 = blockIdx.x * 4;
    const int c = t;
    const int wid = t >> 6, lane = t & 63;

    float y[4];
    #pragma unroll
    for (int r = 0; r < 4; ++r) {
        size_t off = (size_t)(r0 + r) * 256 + c;
        y[r] = x[off] + bo[c] + yP[off] + yP[262144 + off]
             + yP[524288 + off] + yP[786432 + off];
    }

    // LN1
    #pragma unroll
    for (int r = 0; r < 4; ++r) {
        float s = y[r], s2 = y[r] * y[r];
        #pragma unroll
        for (int off = 32; off > 0; off >>= 1) {
            s  += __shfl_xor(s, off);
            s2 += __shfl_xor(s2, off);
        }
        if (lane == 0) { red[wid][r][0] = s; red[wid][r][1] = s2; }
    }
    __syncthreads();
    float t1[4];
    #pragma unroll
    for (int r = 0; r < 4; ++r) {
        float s  = red[0][r][0] + red[1][r][0] + red[2][r][0] + red[3][r][0];
        float s2 = red[0][r][1] + red[1][r][1] + red[2][r][1] + red[3][r][1];
        float mu = s * (1.f / 256.f);
        float var = s2 * (1.f / 256.f) - mu * mu;
        float rs = rsqrtf(var + 1e-5f);
        t1[r] = (y[r] - mu) * rs * g1[c] + b1[c];
    }
    __syncthreads();

    // LN2
    #pragma unroll
    for (int r = 0; r < 4; ++r) {
        float s = t1[r], s2 = t1[r] * t1[r];
        #pragma unroll
        for (int off = 32; off > 0; off >>= 1) {
            s  += __shfl_xor(s, off);
            s2 += __shfl_xor(s2, off);
        }
        if (lane == 0) { red[wid][r][0] = s; red[wid][r][1] = s2; }
    }
    __syncthreads();
    #pragma unroll
    for (int r = 0; r < 4; ++r) {
        float s  = red[0][r][0] + red[1][r][0] + red[2][r][0] + red[3][r][0];
        float s2 = red[0][r][1] + red[1][r][1] + red[2][r][1] + red[3][r][1];
        float mu = s * (1.f / 256.f);
        float var = s2 * (1.f / 256.f) - mu * mu;
        float rs = rsqrtf(var + 1e-5f);
        out[(size_t)(r0 + r) * 256 + c] = (t1[r] - mu) * rs * g2[c] + b2[c];
    }
}

extern "C" void kernel_launch(void* const* d_in, const int* in_sizes, int n_in,
                              void* d_out, int out_size, void* d_ws, size_t ws_size,
                              hipStream_t stream)
{
    const float* x  = (const float*)d_in[0];
    const float* Wq = (const float*)d_in[1];
    const float* bq = (const float*)d_in[2];
    const float* Wk = (const float*)d_in[3];
    const float* bk = (const float*)d_in[4];
    const float* Wv = (const float*)d_in[5];
    const float* bv = (const float*)d_in[6];
    const float* Wr = (const float*)d_in[7];
    const float* br = (const float*)d_in[8];
    const float* Wo = (const float*)d_in[9];
    const float* bo = (const float*)d_in[10];
    const float* g1 = (const float*)d_in[11];
    const float* b1 = (const float*)d_in[12];
    const float* g2 = (const float*)d_in[13];
    const float* b2 = (const float*)d_in[14];
    float* out = (float*)d_out;
    float* ws = (float*)d_ws;

    float* C     = ws;                       // 1024*768
    float* attnw = ws + 786432;              // 1024*256
    float* yP    = ws + 1048576;             // 4 * 1024*256
    unsigned* maxEnc = (unsigned*)(ws + 2097152);  // 512
    unsigned* minEnc = maxEnc + 512;               // 512

    hipMemsetAsync(maxEnc, 0x00, 512 * sizeof(unsigned), stream);
    hipMemsetAsync(minEnc, 0xFF, 512 * sizeof(unsigned), stream);

    k_gemm_proj<<<dim3(16, 16), 256, 0, stream>>>(x, Wq, Wk, Wv, Wr, bq, bk, bv,
                                                  C, maxEnc, minEnc);
    k_attn<<<dim3(32, 8, 2), 256, 0, stream>>>(C, maxEnc, minEnc, br, attnw);
    k_ogemm<<<dim3(16, 4, 4), 256, 0, stream>>>(attnw, Wo, yP);
    k_lnorm<<<256, 256, 0, stream>>>(yP, x, bo, g1, b1, g2, b2, out);
}